// Round 2
// baseline (533.752 us; speedup 1.0000x reference)
//
#include <hip/hip_runtime.h>
#include <hip/hip_bf16.h>

typedef unsigned short ushort_t;
typedef unsigned int uint_t;
typedef __attribute__((ext_vector_type(8))) short bf16x8;
typedef __attribute__((ext_vector_type(4))) float f32x4;

#define MFMA32(a, b, c) __builtin_amdgcn_mfma_f32_16x16x32_bf16(a, b, c, 0, 0, 0)

static constexpr int BATCH = 16;
static constexpr int SEQ   = 4096;   // H*W
static constexpr int CH    = 128;
static constexpr int NGRP  = 32;
static constexpr float EPS = 1e-6f;
// softmax scale folded into exp2 domain AND pre-folded into Q projection:
static constexpr float C2 = 0.08838834764831845f * 1.4426950408889634f;

__device__ inline ushort_t f2bf(float f) {
    uint_t u = __float_as_uint(f);
    u = (u + 0x7fff + ((u >> 16) & 1)) >> 16;
    return (ushort_t)u;
}

__device__ inline float bf2f(ushort_t u) {
    uint_t v = ((uint_t)u) << 16;
    return __uint_as_float(v);
}

// ---------------- GroupNorm partial sums (fp32 input) ----------------
// grid 256 = batch(16) x chunk(16); block 256. Writes RAW (sum, sumsq).
__global__ void gn_partial(const float* __restrict__ x, float* __restrict__ stats) {
    int bid = blockIdx.x;
    int b = bid >> 4, chunk = bid & 15;
    int t = threadIdx.x;
    int c4 = (t & 31) * 4;   // one group = 4 channels
    int rowoff = t >> 5;     // 0..7
    const float* xb = x + (size_t)b * SEQ * CH;
    float s1 = 0.f, s2 = 0.f;
    int base_row = chunk * 256;
    for (int i = 0; i < 32; ++i) {
        int r = base_row + i * 8 + rowoff;
        float4 v = *(const float4*)(xb + (size_t)r * CH + c4);
        s1 += v.x + v.y + v.z + v.w;
        s2 += v.x * v.x + v.y * v.y + v.z * v.z + v.w * v.w;
    }
    __shared__ float red[256][2];
    red[t][0] = s1; red[t][1] = s2;
    __syncthreads();
    if (t < 32) {
        float a1 = 0.f, a2 = 0.f;
        for (int ro = 0; ro < 8; ++ro) {
            a1 += red[ro * 32 + t][0];
            a2 += red[ro * 32 + t][1];
        }
        atomicAdd(&stats[(b * NGRP + t) * 2 + 0], a1);
        atomicAdd(&stats[(b * NGRP + t) * 2 + 1], a2);
    }
}

// ---------------- fused normalize + QKV GEMM (finalize inlined) ----------------
// q output pre-scaled by C2; v written TRANSPOSED: vt[b][d][seq]
__global__ __launch_bounds__(256) void gemm_qkv(const float* __restrict__ x,
                                                const float* __restrict__ stats,
                                                const float* __restrict__ gsc,
                                                const float* __restrict__ gbi,
                                                const float* __restrict__ Wq,
                                                const float* __restrict__ Wk,
                                                const float* __restrict__ Wv,
                                                const float* __restrict__ Bq,
                                                const float* __restrict__ Bk,
                                                const float* __restrict__ Bv,
                                                ushort_t* __restrict__ outq,
                                                ushort_t* __restrict__ outk,
                                                ushort_t* __restrict__ outvt) {
    __shared__ ushort_t lds_a[128][136];  // full 128x128 normalized A tile (bf16)
    __shared__ ushort_t lds_w[128][72];   // W^T half-tile [n][k_local]
    __shared__ float2 gstat[32];
    int t = threadIdx.x;
    int wv = t >> 6, lane = t & 63, quad = lane >> 4, l16 = lane & 15;
    size_t m0 = (size_t)blockIdx.x * 128;
    int batch = (int)(m0 >> 12);
    int seq0  = (int)(m0 & 4095);
    // inline gn_finalize for this batch
    if (t < 32) {
        float sum = stats[(batch * NGRP + t) * 2 + 0];
        float sq  = stats[(batch * NGRP + t) * 2 + 1];
        float mean = sum / 16384.f;
        float var  = sq / 16384.f - mean * mean;
        gstat[t] = float2{mean, __frsqrt_rn(var + EPS)};
    }
    __syncthreads();
    // stage A once, normalizing x -> h in flight
    for (int i = 0; i < 8; ++i) {
        int idx = (t + i * 256) * 8;
        int r = idx >> 7, c = idx & 127;
        size_t row = m0 + r;
        float4 xa = *(const float4*)(x + row * CH + c);
        float4 xc = *(const float4*)(x + row * CH + c + 4);
        float2 stA = gstat[c >> 2];
        float2 stB = gstat[(c >> 2) + 1];
        float4 sA = *(const float4*)(gsc + c), sB = *(const float4*)(gsc + c + 4);
        float4 bA = *(const float4*)(gbi + c), bB = *(const float4*)(gbi + c + 4);
        ushort_t tmp[8];
        tmp[0] = f2bf((xa.x - stA.x) * stA.y * sA.x + bA.x);
        tmp[1] = f2bf((xa.y - stA.x) * stA.y * sA.y + bA.y);
        tmp[2] = f2bf((xa.z - stA.x) * stA.y * sA.z + bA.z);
        tmp[3] = f2bf((xa.w - stA.x) * stA.y * sA.w + bA.w);
        tmp[4] = f2bf((xc.x - stB.x) * stB.y * sB.x + bB.x);
        tmp[5] = f2bf((xc.y - stB.x) * stB.y * sB.y + bB.y);
        tmp[6] = f2bf((xc.z - stB.x) * stB.y * sB.z + bB.z);
        tmp[7] = f2bf((xc.w - stB.x) * stB.y * sB.w + bB.w);
        *(uint4*)&lds_a[r][c] = *(const uint4*)tmp;
    }
    for (int j = 0; j < 3; ++j) {
        const float* W  = (j == 0) ? Wq : (j == 1) ? Wk : Wv;
        const float* Bi = (j == 0) ? Bq : (j == 1) ? Bk : Bv;
        f32x4 acc[2][8] = {};
        for (int kh = 0; kh < 2; ++kh) {
            int k0 = kh * 64;
            __syncthreads();   // protect lds_w reuse (also orders A staging before first read)
            for (int i = 0; i < 8; ++i) {
                int idx = (t + i * 256) * 4;     // flat = kl*128 + n
                int kl = idx >> 7, n = idx & 127;
                float4 wf = *(const float4*)(W + (size_t)(k0 + kl) * CH + n);
                lds_w[n + 0][kl] = f2bf(wf.x);
                lds_w[n + 1][kl] = f2bf(wf.y);
                lds_w[n + 2][kl] = f2bf(wf.z);
                lds_w[n + 3][kl] = f2bf(wf.w);
            }
            __syncthreads();
            for (int ks = 0; ks < 2; ++ks) {
                bf16x8 afrag[2];
                for (int tr = 0; tr < 2; ++tr)
                    afrag[tr] = *(const bf16x8*)&lds_a[wv * 32 + tr * 16 + l16][k0 + ks * 32 + quad * 8];
                for (int tc = 0; tc < 8; ++tc) {
                    bf16x8 bfrag = *(const bf16x8*)&lds_w[tc * 16 + l16][ks * 32 + quad * 8];
                    for (int tr = 0; tr < 2; ++tr)
                        acc[tr][tc] = MFMA32(afrag[tr], bfrag, acc[tr][tc]);
                }
            }
        }
        // epilogue
        for (int tc = 0; tc < 8; ++tc) {
            int col = tc * 16 + l16;
            float bval = Bi[col];
            for (int tr = 0; tr < 2; ++tr) {
                int rl = wv * 32 + tr * 16 + quad * 4;
                for (int r = 0; r < 4; ++r) {
                    float vv = acc[tr][tc][r] + bval;
                    if (j == 0) vv *= C2;   // fold softmax scale into q
                    if (j == 2) {
                        outvt[(size_t)batch * CH * SEQ + (size_t)col * SEQ + seq0 + rl + r] = f2bf(vv);
                    } else {
                        ushort_t* op = (j == 0) ? outq : outk;
                        op[(m0 + rl + r) * CH + col] = f2bf(vv);
                    }
                }
            }
        }
    }
}

// ---------------- flash attention r13: nt=2 + KEY-SPLIT-2 ----------------
// THEORY (r12 post-mortem): halving LDS reads (nt=2) left the wall unchanged
// at VALUBusy 49 / MfmaUtil 29 / Occ 19% -> latency/queueing-bound at 1.5
// waves/SIMD, NOT LDS-throughput-bound.  q-rows/wave x waves/CU is pinned at
// 256, so the only way to raise TLP while keeping nt=2's reuse is to grow the
// grid along the KEY dimension: KSPLIT=2 -> grid 1024.  For 4 blocks/CU to be
// resident, LDS must be < 40KB: KVBLK drops 64->32 (37.9 KB dbuf; total LDS
// traffic, FLOPs, and barrier count are all invariant).  Each block emits an
// fp32 partial O' (normalized) + per-row (mref,lsum); exact merge is folded
// into gemm_out's A-staging.  Expect Occ ~45%, flash ~125-145us.
__global__ __launch_bounds__(256, 4) void flash_attn13(const ushort_t* __restrict__ q,
                                                       const ushort_t* __restrict__ k,
                                                       const ushort_t* __restrict__ vt,
                                                       float* __restrict__ po,
                                                       float2* __restrict__ ml) {
    int bid = blockIdx.x;
    int b = bid & 15, qt = (bid >> 4) & 31, sp = bid >> 9;
    int t = threadIdx.x;
    int wv = t >> 6, lane = t & 63, quad = lane >> 4, l16 = lane & 15;
    const size_t SB = (size_t)SEQ * CH;
    const size_t NEL = (size_t)BATCH * SEQ * CH;
    const ushort_t* qb  = q  + (size_t)b * SB;
    const ushort_t* kb  = k  + (size_t)b * SB + (size_t)sp * 2048 * CH;
    const ushort_t* vtb = vt + (size_t)b * SB + (size_t)sp * 2048;   // [d][seq]

    __shared__ ushort_t lds_k[2][32][136];    // [buf][key][d]          17.4 KB
    __shared__ ushort_t lds_vt[2][128][40];   // [buf][d][key PERMUTED] 20.5 KB

    int qrow_base = qt * 128 + wv * 32;       // 4 waves x 32 q-rows
    // Q^T B-fragments for both 16-row halves (n=qrow=l16, k=d=quad*8+j)
    bf16x8 qfrag[2][4];
#pragma unroll
    for (int nt = 0; nt < 2; ++nt)
#pragma unroll
        for (int ks = 0; ks < 4; ++ks)
            qfrag[nt][ks] = *(const bf16x8*)(qb + (size_t)(qrow_base + nt * 16 + l16) * CH + ks * 32 + quad * 8);

    f32x4 oacc[8][2] = {};   // [mt=d/16][nt]
    float mref[2] = {-1e30f, -1e30f};
    float lsum[2] = {0.f, 0.f};

    // staging geometry: 256 threads stage 32-key K (8KB) and V^T (8KB) tiles,
    // 2 rounds of 16B each
    int kr_row  = t >> 4;          // 0..15 (+16i)
    int kr_col  = (t & 15) * 8;
    int vr_d    = t >> 2;          // 0..63 (+64i)
    int vr_beta = t & 3;
    int vc0 = 16 * (vr_beta & 1) + 4 * ((vr_beta >> 1) & 1);

    const ushort_t* kp = kb + (size_t)kr_row * CH + kr_col;
    const ushort_t* vp = vtb + (size_t)vr_d * SEQ + vr_beta * 8;

    uint4 kr[2], vr[2];
    // preload tile 0 -> regs -> buf 0
#pragma unroll
    for (int i = 0; i < 2; ++i) kr[i] = *(const uint4*)(kp + (size_t)i * 16 * CH);
#pragma unroll
    for (int i = 0; i < 2; ++i) vr[i] = *(const uint4*)(vp + (size_t)i * 64 * SEQ);
    kp += 32 * CH; vp += 32;
#pragma unroll
    for (int i = 0; i < 2; ++i) {
        *(uint4*)&lds_k[0][kr_row + 16 * i][kr_col] = kr[i];
        *(uint2*)&lds_vt[0][vr_d + 64 * i][vc0]     = uint2{vr[i].x, vr[i].y};
        *(uint2*)&lds_vt[0][vr_d + 64 * i][vc0 + 8] = uint2{vr[i].z, vr[i].w};
    }
    __syncthreads();

    for (int it = 0; it < 64; ++it) {
        int cur = it & 1;
        // prefetch tile it+1 -> regs (last iter overruns into the adjacent
        // workspace buffer; values never used)
#pragma unroll
        for (int i = 0; i < 2; ++i) kr[i] = *(const uint4*)(kp + (size_t)i * 16 * CH);
#pragma unroll
        for (int i = 0; i < 2; ++i) vr[i] = *(const uint4*)(vp + (size_t)i * 64 * SEQ);
        kp += 32 * CH; vp += 32;

        // S^T = K·Q^T : per wave 32 keys x 32 qrows (q pre-scaled by C2).
        // Each kf fragment feeds BOTH nt halves.
        f32x4 s[2][2] = {};   // [kt][nt]
#pragma unroll
        for (int ks = 0; ks < 4; ++ks) {
            bf16x8 kf[2];
#pragma unroll
            for (int kt = 0; kt < 2; ++kt)
                kf[kt] = *(const bf16x8*)&lds_k[cur][kt * 16 + l16][ks * 32 + quad * 8];
#pragma unroll
            for (int kt = 0; kt < 2; ++kt) {
                s[kt][0] = MFMA32(kf[kt], qfrag[0][ks], s[kt][0]);
                s[kt][1] = MFMA32(kf[kt], qfrag[1][ks], s[kt][1]);
            }
        }

        // lazy online softmax (exp2 domain), independently per nt half;
        // one wave-wide vote covers both halves (~once per kernel)
        bf16x8 pkp[2];   // [nt] single 32-key fragment each
        {
            float mt_[2];
#pragma unroll
            for (int nt = 0; nt < 2; ++nt) {
                float m = -1e30f;
#pragma unroll
                for (int kt = 0; kt < 2; ++kt)
#pragma unroll
                    for (int r = 0; r < 4; ++r)
                        m = fmaxf(m, s[kt][nt][r]);
                m = fmaxf(m, __shfl_xor(m, 16, 64));
                m = fmaxf(m, __shfl_xor(m, 32, 64));
                mt_[nt] = m;
            }
            if (__any((mt_[0] > mref[0] + 30.f) || (mt_[1] > mref[1] + 30.f))) {
#pragma unroll
                for (int nt = 0; nt < 2; ++nt) {
                    float mnew = fmaxf(mref[nt], mt_[nt]);
                    float alpha = exp2f(mref[nt] - mnew);
                    lsum[nt] *= alpha;
#pragma unroll
                    for (int mt = 0; mt < 8; ++mt)
#pragma unroll
                        for (int r = 0; r < 4; ++r)
                            oacc[mt][nt][r] *= alpha;
                    mref[nt] = mnew;
                }
            }
#pragma unroll
            for (int nt = 0; nt < 2; ++nt) {
                float ps = 0.f;
                uint_t pb[4];
#pragma unroll
                for (int kt = 0; kt < 2; ++kt) {
                    float p0 = exp2f(s[kt][nt][0] - mref[nt]);
                    float p1 = exp2f(s[kt][nt][1] - mref[nt]);
                    float p2 = exp2f(s[kt][nt][2] - mref[nt]);
                    float p3 = exp2f(s[kt][nt][3] - mref[nt]);
                    ps += (p0 + p1) + (p2 + p3);
                    __hip_bfloat162 h01 = __float22bfloat162_rn(float2{p0, p1});
                    __hip_bfloat162 h23 = __float22bfloat162_rn(float2{p2, p3});
                    __builtin_memcpy(&pb[kt * 2 + 0], &h01, 4);
                    __builtin_memcpy(&pb[kt * 2 + 1], &h23, 4);
                }
                ps += __shfl_xor(ps, 16, 64);
                ps += __shfl_xor(ps, 32, 64);
                lsum[nt] += ps;
                __builtin_memcpy(&pkp[nt], &pb[0], 16);
            }
        }

        // O^T += V^T · P^T  via MFMA32 (V^T columns pre-permuted to match pkp).
        // Each vf fragment read feeds BOTH nt halves.
#pragma unroll
        for (int mt = 0; mt < 8; ++mt) {
            bf16x8 vf = *(const bf16x8*)&lds_vt[cur][mt * 16 + l16][quad * 8];
            oacc[mt][0] = MFMA32(vf, pkp[0], oacc[mt][0]);
            oacc[mt][1] = MFMA32(vf, pkp[1], oacc[mt][1]);
        }

        // write prefetched tile -> other buffer (read last at iter it-1;
        // the barrier below orders it for iter it+1)
        int nxt = cur ^ 1;
#pragma unroll
        for (int i = 0; i < 2; ++i) {
            *(uint4*)&lds_k[nxt][kr_row + 16 * i][kr_col] = kr[i];
            *(uint2*)&lds_vt[nxt][vr_d + 64 * i][vc0]     = uint2{vr[i].x, vr[i].y};
            *(uint2*)&lds_vt[nxt][vr_d + 64 * i][vc0 + 8] = uint2{vr[i].z, vr[i].w};
        }
        __syncthreads();   // single barrier per iteration
    }

    // epilogue: partial O' = O^T / l (fp32, 16B stores) + per-row (mref,lsum)
#pragma unroll
    for (int nt = 0; nt < 2; ++nt) {
        float inv = 1.f / lsum[nt];
        size_t row = (size_t)b * SEQ + qrow_base + nt * 16 + l16;
        float* prow = po + (size_t)sp * NEL + row * CH;
#pragma unroll
        for (int mt = 0; mt < 8; ++mt) {
            float4 st;
            st.x = oacc[mt][nt][0] * inv;
            st.y = oacc[mt][nt][1] * inv;
            st.z = oacc[mt][nt][2] * inv;
            st.w = oacc[mt][nt][3] * inv;
            *(float4*)&prow[mt * 16 + quad * 4] = st;
        }
        if (quad == 0)
            ml[(size_t)sp * (BATCH * SEQ) + row] = float2{mref[nt], lsum[nt]};
    }
}

// ---------------- final GEMM: out = merge(P0,P1) @ W + bias + resid ----------------
// Split-K merge folded into A-staging: per-row alphas from (m,l) pairs, exact
// softmax algebra, fp32 until the single bf16 round at LDS staging.
__global__ __launch_bounds__(256) void gemm_out(const float* __restrict__ P0,
                                                const float* __restrict__ P1,
                                                const float2* __restrict__ ML,
                                                const float* __restrict__ W,
                                                const float* __restrict__ bias,
                                                const float* __restrict__ resid,
                                                float* __restrict__ out) {
    __shared__ ushort_t lds_a[128][72];
    __shared__ ushort_t lds_w[128][72];
    __shared__ float lds_al[128][2];
    int t = threadIdx.x;
    int wv = t >> 6, lane = t & 63, quad = lane >> 4, l16 = lane & 15;
    size_t m0 = (size_t)blockIdx.x * 128;
    const int ROWS = BATCH * SEQ;
    if (t < 128) {
        float2 s0 = ML[m0 + t];
        float2 s1 = ML[ROWS + m0 + t];
        float m = fmaxf(s0.x, s1.x);
        float w0 = s0.y * exp2f(s0.x - m);
        float w1 = s1.y * exp2f(s1.x - m);
        float inv = 1.f / (w0 + w1);
        lds_al[t][0] = w0 * inv;
        lds_al[t][1] = w1 * inv;
    }
    f32x4 acc[2][8] = {};
    for (int kh = 0; kh < 2; ++kh) {
        int k0 = kh * 64;
        __syncthreads();   // also orders lds_al for first use
        for (int i = 0; i < 8; ++i) {
            int idx = (t + i * 256) * 4;
            int r = idx >> 6, c = idx & 63;
            float4 a0 = *(const float4*)(P0 + (m0 + r) * CH + k0 + c);
            float4 a1 = *(const float4*)(P1 + (m0 + r) * CH + k0 + c);
            float al0 = lds_al[r][0], al1 = lds_al[r][1];
            ushort_t tmp[4];
            tmp[0] = f2bf(a0.x * al0 + a1.x * al1);
            tmp[1] = f2bf(a0.y * al0 + a1.y * al1);
            tmp[2] = f2bf(a0.z * al0 + a1.z * al1);
            tmp[3] = f2bf(a0.w * al0 + a1.w * al1);
            *(uint2*)&lds_a[r][c] = *(const uint2*)tmp;
        }
        for (int i = 0; i < 8; ++i) {
            int idx = (t + i * 256) * 4;
            int kl = idx >> 7, n = idx & 127;
            float4 wf = *(const float4*)(W + (size_t)(k0 + kl) * CH + n);
            lds_w[n + 0][kl] = f2bf(wf.x);
            lds_w[n + 1][kl] = f2bf(wf.y);
            lds_w[n + 2][kl] = f2bf(wf.z);
            lds_w[n + 3][kl] = f2bf(wf.w);
        }
        __syncthreads();
        for (int ks = 0; ks < 2; ++ks) {
            bf16x8 afrag[2];
            for (int tr = 0; tr < 2; ++tr)
                afrag[tr] = *(const bf16x8*)&lds_a[wv * 32 + tr * 16 + l16][ks * 32 + quad * 8];
            for (int tc = 0; tc < 8; ++tc) {
                bf16x8 bfrag = *(const bf16x8*)&lds_w[tc * 16 + l16][ks * 32 + quad * 8];
                for (int tr = 0; tr < 2; ++tr)
                    acc[tr][tc] = MFMA32(afrag[tr], bfrag, acc[tr][tc]);
            }
        }
    }
    for (int tc = 0; tc < 8; ++tc) {
        int col = tc * 16 + l16;
        float bval = bias[col];
        for (int tr = 0; tr < 2; ++tr) {
            int rl = wv * 32 + tr * 16 + quad * 4;
            for (int r = 0; r < 4; ++r) {
                size_t row = m0 + rl + r;
                out[row * CH + col] = acc[tr][tc][r] + bval + resid[row * CH + col];
            }
        }
    }
}

extern "C" void kernel_launch(void* const* d_in, const int* in_sizes, int n_in,
                              void* d_out, int out_size, void* d_ws, size_t ws_size,
                              hipStream_t stream) {
    const float* x   = (const float*)d_in[0];
    const float* gsc = (const float*)d_in[1];
    const float* gbi = (const float*)d_in[2];
    const float* wq  = (const float*)d_in[3];
    const float* bq  = (const float*)d_in[4];
    const float* wk  = (const float*)d_in[5];
    const float* bk  = (const float*)d_in[6];
    const float* wvp = (const float*)d_in[7];
    const float* bv  = (const float*)d_in[8];
    const float* wo  = (const float*)d_in[9];
    const float* bo  = (const float*)d_in[10];
    float* outp = (float*)d_out;

    const size_t NELEM = (size_t)BATCH * SEQ * CH;  // 8388608
    float*    stats = (float*)d_ws;
    ushort_t* qbuf  = (ushort_t*)((char*)d_ws + 4096);
    ushort_t* kbuf  = qbuf + NELEM;
    ushort_t* vtbuf = kbuf + NELEM;
    float*    pbuf  = (float*)(vtbuf + NELEM);      // 2 x NELEM fp32 partials
    float2*   mlbuf = (float2*)(pbuf + 2 * NELEM);  // 2 x 65536 (m,l) pairs
    // note: flash_attn13 prefetches one tile past K/V^T ends (reads land in the
    // adjacent workspace buffer; values unused) — keep pbuf allocated after vtbuf.

    hipMemsetAsync(stats, 0, BATCH * NGRP * 2 * sizeof(float), stream);
    gn_partial<<<256, 256, 0, stream>>>(x, stats);
    gemm_qkv<<<512, 256, 0, stream>>>(x, stats, gsc, gbi, wq, wk, wvp, bq, bk, bv,
                                      qbuf, kbuf, vtbuf);
    flash_attn13<<<1024, 256, 0, stream>>>(qbuf, kbuf, vtbuf, pbuf, mlbuf);
    gemm_out<<<512, 256, 0, stream>>>(pbuf, pbuf + NELEM, mlbuf, wo, bo, x, outp);
}

// Round 3
// 344.640 us; speedup vs baseline: 1.5487x; 1.5487x over previous
//
#include <hip/hip_runtime.h>
#include <hip/hip_bf16.h>

typedef unsigned short ushort_t;
typedef unsigned int uint_t;
typedef __attribute__((ext_vector_type(8))) short bf16x8;
typedef __attribute__((ext_vector_type(4))) float f32x4;

#define MFMA32(a, b, c) __builtin_amdgcn_mfma_f32_16x16x32_bf16(a, b, c, 0, 0, 0)

static constexpr int BATCH = 16;
static constexpr int SEQ   = 4096;   // H*W
static constexpr int CH    = 128;
static constexpr int NGRP  = 32;
static constexpr float EPS = 1e-6f;
// softmax scale folded into exp2 domain AND pre-folded into Q projection:
static constexpr float C2 = 0.08838834764831845f * 1.4426950408889634f;

__device__ inline ushort_t f2bf(float f) {
    uint_t u = __float_as_uint(f);
    u = (u + 0x7fff + ((u >> 16) & 1)) >> 16;
    return (ushort_t)u;
}

// ---------------- GroupNorm partial sums (fp32 input) ----------------
// grid 256 = batch(16) x chunk(16); block 256. Writes RAW (sum, sumsq).
__global__ void gn_partial(const float* __restrict__ x, float* __restrict__ stats) {
    int bid = blockIdx.x;
    int b = bid >> 4, chunk = bid & 15;
    int t = threadIdx.x;
    int c4 = (t & 31) * 4;   // one group = 4 channels
    int rowoff = t >> 5;     // 0..7
    const float* xb = x + (size_t)b * SEQ * CH;
    float s1 = 0.f, s2 = 0.f;
    int base_row = chunk * 256;
    for (int i = 0; i < 32; ++i) {
        int r = base_row + i * 8 + rowoff;
        float4 v = *(const float4*)(xb + (size_t)r * CH + c4);
        s1 += v.x + v.y + v.z + v.w;
        s2 += v.x * v.x + v.y * v.y + v.z * v.z + v.w * v.w;
    }
    __shared__ float red[256][2];
    red[t][0] = s1; red[t][1] = s2;
    __syncthreads();
    if (t < 32) {
        float a1 = 0.f, a2 = 0.f;
        for (int ro = 0; ro < 8; ++ro) {
            a1 += red[ro * 32 + t][0];
            a2 += red[ro * 32 + t][1];
        }
        atomicAdd(&stats[(b * NGRP + t) * 2 + 0], a1);
        atomicAdd(&stats[(b * NGRP + t) * 2 + 1], a2);
    }
}

// ---------------- fused normalize + QKV GEMM (finalize inlined) ----------------
// q output pre-scaled by C2; v written TRANSPOSED: vt[b][d][seq]
__global__ __launch_bounds__(256) void gemm_qkv(const float* __restrict__ x,
                                                const float* __restrict__ stats,
                                                const float* __restrict__ gsc,
                                                const float* __restrict__ gbi,
                                                const float* __restrict__ Wq,
                                                const float* __restrict__ Wk,
                                                const float* __restrict__ Wv,
                                                const float* __restrict__ Bq,
                                                const float* __restrict__ Bk,
                                                const float* __restrict__ Bv,
                                                ushort_t* __restrict__ outq,
                                                ushort_t* __restrict__ outk,
                                                ushort_t* __restrict__ outvt) {
    __shared__ ushort_t lds_a[128][136];  // full 128x128 normalized A tile (bf16)
    __shared__ ushort_t lds_w[128][72];   // W^T half-tile [n][k_local]
    __shared__ float2 gstat[32];
    int t = threadIdx.x;
    int wv = t >> 6, lane = t & 63, quad = lane >> 4, l16 = lane & 15;
    size_t m0 = (size_t)blockIdx.x * 128;
    int batch = (int)(m0 >> 12);
    int seq0  = (int)(m0 & 4095);
    // inline gn_finalize for this batch
    if (t < 32) {
        float sum = stats[(batch * NGRP + t) * 2 + 0];
        float sq  = stats[(batch * NGRP + t) * 2 + 1];
        float mean = sum / 16384.f;
        float var  = sq / 16384.f - mean * mean;
        gstat[t] = float2{mean, __frsqrt_rn(var + EPS)};
    }
    __syncthreads();
    // stage A once, normalizing x -> h in flight
    for (int i = 0; i < 8; ++i) {
        int idx = (t + i * 256) * 8;
        int r = idx >> 7, c = idx & 127;
        size_t row = m0 + r;
        float4 xa = *(const float4*)(x + row * CH + c);
        float4 xc = *(const float4*)(x + row * CH + c + 4);
        float2 stA = gstat[c >> 2];
        float2 stB = gstat[(c >> 2) + 1];
        float4 sA = *(const float4*)(gsc + c), sB = *(const float4*)(gsc + c + 4);
        float4 bA = *(const float4*)(gbi + c), bB = *(const float4*)(gbi + c + 4);
        ushort_t tmp[8];
        tmp[0] = f2bf((xa.x - stA.x) * stA.y * sA.x + bA.x);
        tmp[1] = f2bf((xa.y - stA.x) * stA.y * sA.y + bA.y);
        tmp[2] = f2bf((xa.z - stA.x) * stA.y * sA.z + bA.z);
        tmp[3] = f2bf((xa.w - stA.x) * stA.y * sA.w + bA.w);
        tmp[4] = f2bf((xc.x - stB.x) * stB.y * sB.x + bB.x);
        tmp[5] = f2bf((xc.y - stB.x) * stB.y * sB.y + bB.y);
        tmp[6] = f2bf((xc.z - stB.x) * stB.y * sB.z + bB.z);
        tmp[7] = f2bf((xc.w - stB.x) * stB.y * sB.w + bB.w);
        *(uint4*)&lds_a[r][c] = *(const uint4*)tmp;
    }
    for (int j = 0; j < 3; ++j) {
        const float* W  = (j == 0) ? Wq : (j == 1) ? Wk : Wv;
        const float* Bi = (j == 0) ? Bq : (j == 1) ? Bk : Bv;
        f32x4 acc[2][8] = {};
        for (int kh = 0; kh < 2; ++kh) {
            int k0 = kh * 64;
            __syncthreads();   // protect lds_w reuse (also orders A staging before first read)
            for (int i = 0; i < 8; ++i) {
                int idx = (t + i * 256) * 4;     // flat = kl*128 + n
                int kl = idx >> 7, n = idx & 127;
                float4 wf = *(const float4*)(W + (size_t)(k0 + kl) * CH + n);
                lds_w[n + 0][kl] = f2bf(wf.x);
                lds_w[n + 1][kl] = f2bf(wf.y);
                lds_w[n + 2][kl] = f2bf(wf.z);
                lds_w[n + 3][kl] = f2bf(wf.w);
            }
            __syncthreads();
            for (int ks = 0; ks < 2; ++ks) {
                bf16x8 afrag[2];
                for (int tr = 0; tr < 2; ++tr)
                    afrag[tr] = *(const bf16x8*)&lds_a[wv * 32 + tr * 16 + l16][k0 + ks * 32 + quad * 8];
                for (int tc = 0; tc < 8; ++tc) {
                    bf16x8 bfrag = *(const bf16x8*)&lds_w[tc * 16 + l16][ks * 32 + quad * 8];
                    for (int tr = 0; tr < 2; ++tr)
                        acc[tr][tc] = MFMA32(afrag[tr], bfrag, acc[tr][tc]);
                }
            }
        }
        // epilogue
        for (int tc = 0; tc < 8; ++tc) {
            int col = tc * 16 + l16;
            float bval = Bi[col];
            for (int tr = 0; tr < 2; ++tr) {
                int rl = wv * 32 + tr * 16 + quad * 4;
                for (int r = 0; r < 4; ++r) {
                    float vv = acc[tr][tc][r] + bval;
                    if (j == 0) vv *= C2;   // fold softmax scale into q
                    if (j == 2) {
                        outvt[(size_t)batch * CH * SEQ + (size_t)col * SEQ + seq0 + rl + r] = f2bf(vv);
                    } else {
                        ushort_t* op = (j == 0) ? outq : outk;
                        op[(m0 + rl + r) * CH + col] = f2bf(vv);
                    }
                }
            }
        }
    }
}

// ---------------- flash attention r14: nt=2 + UNNORMALIZED exp2 softmax ------
// r13 post-mortem: split-K raised Occ to 44% but broke the per-XCD L2 budget
// (FETCH 26MB->601MB, fabric-bound) -> reverted.  r12 is latency-bound on the
// per-iteration serial chain (Occ 19%, no pipe >50%).  The longest removable
// segment is the online-softmax max machinery: 32 fmax + 4 shfl round-trips
// (~100cy DS latency each, serial) + vote + branch per iter, all to guard a
// rescale that ~never fires.  NUMERICS: S = (q.k)*0.127 with GN-normalized
// inputs -> |S| <~ 15 over 2^32 samples; exp2(S) <= 2^15, lsum <= 2^27 — all
// comfortably inside fp32/bf16 range, and softmax is shift-invariant.  So:
// p = exp2(S) UNNORMALIZED, no max tracking at all; per-lane partial row-sums
// accumulate in a register and cross-lane-reduce ONCE in the epilogue.
__global__ __launch_bounds__(256, 2) void flash_attn14(const ushort_t* __restrict__ q,
                                                       const ushort_t* __restrict__ k,
                                                       const ushort_t* __restrict__ vt,
                                                       ushort_t* __restrict__ o) {
    int bid = blockIdx.x;
    int b = bid & 15, qt = bid >> 4;
    int t = threadIdx.x;
    int wv = t >> 6, lane = t & 63, quad = lane >> 4, l16 = lane & 15;
    const size_t SB = (size_t)SEQ * CH;
    const ushort_t* qb  = q  + (size_t)b * SB;
    const ushort_t* kb  = k  + (size_t)b * SB;
    const ushort_t* vtb = vt + (size_t)b * SB;   // [d][seq]

    __shared__ ushort_t lds_k[2][64][136];    // [buf][key][d]
    __shared__ ushort_t lds_vt[2][128][72];   // [buf][d][key_local PERMUTED]

    int qrow_base = qt * 128 + wv * 32;       // 4 waves x 32 q-rows
    // Q^T B-fragments for both 16-row halves (n=qrow=l16, k=d=quad*8+j)
    bf16x8 qfrag[2][4];
#pragma unroll
    for (int nt = 0; nt < 2; ++nt)
#pragma unroll
        for (int ks = 0; ks < 4; ++ks)
            qfrag[nt][ks] = *(const bf16x8*)(qb + (size_t)(qrow_base + nt * 16 + l16) * CH + ks * 32 + quad * 8);

    f32x4 oacc[8][2] = {};   // [mt=d/16][nt]
    float psum[2] = {0.f, 0.f};   // per-lane partial row-sums (reduced at end)

    // staging geometry (256 threads stage the full 64-key K and V^T tiles:
    // 4 rounds of 16B each)
    int kr_row  = t >> 4;          // 0..15 (+16i)
    int kr_col  = (t & 15) * 8;
    int vr_d    = t >> 3;          // 0..31 (+32i)
    int vr_beta = t & 7;
    int vc0 = 32 * (vr_beta >> 2) + 16 * (vr_beta & 1) + 4 * ((vr_beta >> 1) & 1);

    const ushort_t* kp = kb + (size_t)kr_row * CH + kr_col;
    const ushort_t* vp = vtb + (size_t)vr_d * SEQ + vr_beta * 8;

    uint4 kr[4], vr[4];
    // preload tile 0 -> regs -> buf 0
#pragma unroll
    for (int i = 0; i < 4; ++i) kr[i] = *(const uint4*)(kp + (size_t)i * 16 * CH);
#pragma unroll
    for (int i = 0; i < 4; ++i) vr[i] = *(const uint4*)(vp + (size_t)i * 32 * SEQ);
    kp += 64 * CH; vp += 64;
#pragma unroll
    for (int i = 0; i < 4; ++i) {
        *(uint4*)&lds_k[0][kr_row + 16 * i][kr_col] = kr[i];
        *(uint2*)&lds_vt[0][vr_d + 32 * i][vc0]     = uint2{vr[i].x, vr[i].y};
        *(uint2*)&lds_vt[0][vr_d + 32 * i][vc0 + 8] = uint2{vr[i].z, vr[i].w};
    }
    __syncthreads();

    for (int it = 0; it < 64; ++it) {
        int cur = it & 1;
        // prefetch tile it+1 -> regs (at it=63 overruns into the adjacent
        // workspace buffer; values never used)
#pragma unroll
        for (int i = 0; i < 4; ++i) kr[i] = *(const uint4*)(kp + (size_t)i * 16 * CH);
#pragma unroll
        for (int i = 0; i < 4; ++i) vr[i] = *(const uint4*)(vp + (size_t)i * 32 * SEQ);
        kp += 64 * CH; vp += 64;

        // S^T = K·Q^T : per wave 64 keys x 32 qrows (q pre-scaled by C2).
        // Each kf fragment read feeds BOTH nt halves.
        f32x4 s[4][2] = {};   // [kt][nt]
#pragma unroll
        for (int ks = 0; ks < 4; ++ks) {
            bf16x8 kf[4];
#pragma unroll
            for (int kt = 0; kt < 4; ++kt)
                kf[kt] = *(const bf16x8*)&lds_k[cur][kt * 16 + l16][ks * 32 + quad * 8];
#pragma unroll
            for (int kt = 0; kt < 4; ++kt) {
                s[kt][0] = MFMA32(kf[kt], qfrag[0][ks], s[kt][0]);
                s[kt][1] = MFMA32(kf[kt], qfrag[1][ks], s[kt][1]);
            }
        }

        // unnormalized softmax numerator: p = exp2(S), no max, no shuffles,
        // no branch.  Row-sum partials accumulate per-lane in psum[].
        bf16x8 pkp[2][2];   // [nt][half]
#pragma unroll
        for (int nt = 0; nt < 2; ++nt) {
            float ps = 0.f;
            uint_t pb[8];
#pragma unroll
            for (int kt = 0; kt < 4; ++kt) {
                float p0 = exp2f(s[kt][nt][0]);
                float p1 = exp2f(s[kt][nt][1]);
                float p2 = exp2f(s[kt][nt][2]);
                float p3 = exp2f(s[kt][nt][3]);
                ps += (p0 + p1) + (p2 + p3);
                __hip_bfloat162 h01 = __float22bfloat162_rn(float2{p0, p1});
                __hip_bfloat162 h23 = __float22bfloat162_rn(float2{p2, p3});
                __builtin_memcpy(&pb[kt * 2 + 0], &h01, 4);
                __builtin_memcpy(&pb[kt * 2 + 1], &h23, 4);
            }
            psum[nt] += ps;
            __builtin_memcpy(&pkp[nt][0], &pb[0], 16);
            __builtin_memcpy(&pkp[nt][1], &pb[4], 16);
        }

        // O^T += V^T · P^T  via MFMA32 (V^T columns pre-permuted to match pkp).
        // Each vf fragment read feeds BOTH nt halves.
#pragma unroll
        for (int mt = 0; mt < 8; ++mt) {
            bf16x8 vf0 = *(const bf16x8*)&lds_vt[cur][mt * 16 + l16][quad * 8];
            bf16x8 vf1 = *(const bf16x8*)&lds_vt[cur][mt * 16 + l16][32 + quad * 8];
            oacc[mt][0] = MFMA32(vf0, pkp[0][0], oacc[mt][0]);
            oacc[mt][0] = MFMA32(vf1, pkp[0][1], oacc[mt][0]);
            oacc[mt][1] = MFMA32(vf0, pkp[1][0], oacc[mt][1]);
            oacc[mt][1] = MFMA32(vf1, pkp[1][1], oacc[mt][1]);
        }

        // write prefetched tile -> other buffer (read last at iter it-1;
        // the barrier below orders it for iter it+1)
        int nxt = cur ^ 1;
#pragma unroll
        for (int i = 0; i < 4; ++i) {
            *(uint4*)&lds_k[nxt][kr_row + 16 * i][kr_col] = kr[i];
            *(uint2*)&lds_vt[nxt][vr_d + 32 * i][vc0]     = uint2{vr[i].x, vr[i].y};
            *(uint2*)&lds_vt[nxt][vr_d + 32 * i][vc0 + 8] = uint2{vr[i].z, vr[i].w};
        }
        __syncthreads();   // single barrier per iteration
    }

    // epilogue: cross-lane row-sum reduce (ONCE), then O[qrow][d] = O^T / l
#pragma unroll
    for (int nt = 0; nt < 2; ++nt) {
        float tot = psum[nt];
        tot += __shfl_xor(tot, 16, 64);
        tot += __shfl_xor(tot, 32, 64);
        float inv = 1.f / tot;
        size_t row = (size_t)b * SEQ + qrow_base + nt * 16 + l16;
#pragma unroll
        for (int mt = 0; mt < 8; ++mt) {
            ushort_t tmp[4];
#pragma unroll
            for (int r = 0; r < 4; ++r) tmp[r] = f2bf(oacc[mt][nt][r] * inv);
            *(uint2*)&o[row * CH + mt * 16 + quad * 4] = *(const uint2*)tmp;
        }
    }
}

// ---------------- final GEMM: out = A_bf16 @ W + bias + resid (fp32 out) ----------------
__global__ __launch_bounds__(256) void gemm_out(const ushort_t* __restrict__ A,
                                                const float* __restrict__ W,
                                                const float* __restrict__ bias,
                                                const float* __restrict__ resid,
                                                float* __restrict__ out) {
    __shared__ ushort_t lds_a[128][72];
    __shared__ ushort_t lds_w[128][72];
    int t = threadIdx.x;
    int wv = t >> 6, lane = t & 63, quad = lane >> 4, l16 = lane & 15;
    size_t m0 = (size_t)blockIdx.x * 128;
    f32x4 acc[2][8] = {};
    for (int kh = 0; kh < 2; ++kh) {
        int k0 = kh * 64;
        __syncthreads();
        for (int i = 0; i < 4; ++i) {
            int idx = (t + i * 256) * 8;
            int r = idx >> 6, c = idx & 63;
            *(uint4*)&lds_a[r][c] = *(const uint4*)(A + (m0 + r) * CH + k0 + c);
        }
        for (int i = 0; i < 8; ++i) {
            int idx = (t + i * 256) * 4;
            int kl = idx >> 7, n = idx & 127;
            float4 wf = *(const float4*)(W + (size_t)(k0 + kl) * CH + n);
            lds_w[n + 0][kl] = f2bf(wf.x);
            lds_w[n + 1][kl] = f2bf(wf.y);
            lds_w[n + 2][kl] = f2bf(wf.z);
            lds_w[n + 3][kl] = f2bf(wf.w);
        }
        __syncthreads();
        for (int ks = 0; ks < 2; ++ks) {
            bf16x8 afrag[2];
            for (int tr = 0; tr < 2; ++tr)
                afrag[tr] = *(const bf16x8*)&lds_a[wv * 32 + tr * 16 + l16][ks * 32 + quad * 8];
            for (int tc = 0; tc < 8; ++tc) {
                bf16x8 bfrag = *(const bf16x8*)&lds_w[tc * 16 + l16][ks * 32 + quad * 8];
                for (int tr = 0; tr < 2; ++tr)
                    acc[tr][tc] = MFMA32(afrag[tr], bfrag, acc[tr][tc]);
            }
        }
    }
    for (int tc = 0; tc < 8; ++tc) {
        int col = tc * 16 + l16;
        float bval = bias[col];
        for (int tr = 0; tr < 2; ++tr) {
            int rl = wv * 32 + tr * 16 + quad * 4;
            for (int r = 0; r < 4; ++r) {
                size_t row = m0 + rl + r;
                out[row * CH + col] = acc[tr][tc][r] + bval + resid[row * CH + col];
            }
        }
    }
}

extern "C" void kernel_launch(void* const* d_in, const int* in_sizes, int n_in,
                              void* d_out, int out_size, void* d_ws, size_t ws_size,
                              hipStream_t stream) {
    const float* x   = (const float*)d_in[0];
    const float* gsc = (const float*)d_in[1];
    const float* gbi = (const float*)d_in[2];
    const float* wq  = (const float*)d_in[3];
    const float* bq  = (const float*)d_in[4];
    const float* wk  = (const float*)d_in[5];
    const float* bk  = (const float*)d_in[6];
    const float* wvp = (const float*)d_in[7];
    const float* bv  = (const float*)d_in[8];
    const float* wo  = (const float*)d_in[9];
    const float* bo  = (const float*)d_in[10];
    float* outp = (float*)d_out;

    const size_t NELEM = (size_t)BATCH * SEQ * CH;  // 8388608
    float*    stats = (float*)d_ws;
    ushort_t* qbuf  = (ushort_t*)((char*)d_ws + 4096);
    ushort_t* kbuf  = qbuf + NELEM;
    ushort_t* vtbuf = kbuf + NELEM;
    ushort_t* abuf  = vtbuf + NELEM;   // attention output
    // note: flash_attn14 prefetches one tile past K/V^T ends (reads land in the
    // adjacent workspace buffer; values unused) — keep abuf allocated after vtbuf.

    hipMemsetAsync(stats, 0, BATCH * NGRP * 2 * sizeof(float), stream);
    gn_partial<<<256, 256, 0, stream>>>(x, stats);
    gemm_qkv<<<512, 256, 0, stream>>>(x, stats, gsc, gbi, wq, wk, wvp, bq, bk, bv,
                                      qbuf, kbuf, vtbuf);
    flash_attn14<<<512, 256, 0, stream>>>(qbuf, kbuf, vtbuf, abuf);
    gemm_out<<<512, 256, 0, stream>>>(abuf, wo, bo, x, outp);
}

// Round 4
// 323.956 us; speedup vs baseline: 1.6476x; 1.0638x over previous
//
#include <hip/hip_runtime.h>
#include <hip/hip_bf16.h>

typedef unsigned short ushort_t;
typedef unsigned int uint_t;
typedef __attribute__((ext_vector_type(8))) short bf16x8;
typedef __attribute__((ext_vector_type(4))) float f32x4;

#define MFMA32(a, b, c) __builtin_amdgcn_mfma_f32_16x16x32_bf16(a, b, c, 0, 0, 0)

static constexpr int BATCH = 16;
static constexpr int SEQ   = 4096;   // H*W
static constexpr int CH    = 128;
static constexpr int NGRP  = 32;
static constexpr float EPS = 1e-6f;
// softmax scale folded into exp2 domain AND pre-folded into Q projection:
static constexpr float C2 = 0.08838834764831845f * 1.4426950408889634f;

__device__ inline ushort_t f2bf(float f) {
    uint_t u = __float_as_uint(f);
    u = (u + 0x7fff + ((u >> 16) & 1)) >> 16;
    return (ushort_t)u;
}

// ---------------- GroupNorm partial sums (fp32 input) ----------------
// grid 256 = batch(16) x chunk(16); block 256. Writes RAW (sum, sumsq).
__global__ void gn_partial(const float* __restrict__ x, float* __restrict__ stats) {
    int bid = blockIdx.x;
    int b = bid >> 4, chunk = bid & 15;
    int t = threadIdx.x;
    int c4 = (t & 31) * 4;   // one group = 4 channels
    int rowoff = t >> 5;     // 0..7
    const float* xb = x + (size_t)b * SEQ * CH;
    float s1 = 0.f, s2 = 0.f;
    int base_row = chunk * 256;
    for (int i = 0; i < 32; ++i) {
        int r = base_row + i * 8 + rowoff;
        float4 v = *(const float4*)(xb + (size_t)r * CH + c4);
        s1 += v.x + v.y + v.z + v.w;
        s2 += v.x * v.x + v.y * v.y + v.z * v.z + v.w * v.w;
    }
    __shared__ float red[256][2];
    red[t][0] = s1; red[t][1] = s2;
    __syncthreads();
    if (t < 32) {
        float a1 = 0.f, a2 = 0.f;
        for (int ro = 0; ro < 8; ++ro) {
            a1 += red[ro * 32 + t][0];
            a2 += red[ro * 32 + t][1];
        }
        atomicAdd(&stats[(b * NGRP + t) * 2 + 0], a1);
        atomicAdd(&stats[(b * NGRP + t) * 2 + 1], a2);
    }
}

// ---------------- fused normalize + QKV GEMM (finalize inlined) ----------------
// q output pre-scaled by C2; v written TRANSPOSED: vt[b][d][seq]
__global__ __launch_bounds__(256) void gemm_qkv(const float* __restrict__ x,
                                                const float* __restrict__ stats,
                                                const float* __restrict__ gsc,
                                                const float* __restrict__ gbi,
                                                const float* __restrict__ Wq,
                                                const float* __restrict__ Wk,
                                                const float* __restrict__ Wv,
                                                const float* __restrict__ Bq,
                                                const float* __restrict__ Bk,
                                                const float* __restrict__ Bv,
                                                ushort_t* __restrict__ outq,
                                                ushort_t* __restrict__ outk,
                                                ushort_t* __restrict__ outvt) {
    __shared__ ushort_t lds_a[128][136];  // full 128x128 normalized A tile (bf16)
    __shared__ ushort_t lds_w[128][72];   // W^T half-tile [n][k_local]
    __shared__ float2 gstat[32];
    int t = threadIdx.x;
    int wv = t >> 6, lane = t & 63, quad = lane >> 4, l16 = lane & 15;
    size_t m0 = (size_t)blockIdx.x * 128;
    int batch = (int)(m0 >> 12);
    int seq0  = (int)(m0 & 4095);
    // inline gn_finalize for this batch
    if (t < 32) {
        float sum = stats[(batch * NGRP + t) * 2 + 0];
        float sq  = stats[(batch * NGRP + t) * 2 + 1];
        float mean = sum / 16384.f;
        float var  = sq / 16384.f - mean * mean;
        gstat[t] = float2{mean, __frsqrt_rn(var + EPS)};
    }
    __syncthreads();
    // stage A once, normalizing x -> h in flight
    for (int i = 0; i < 8; ++i) {
        int idx = (t + i * 256) * 8;
        int r = idx >> 7, c = idx & 127;
        size_t row = m0 + r;
        float4 xa = *(const float4*)(x + row * CH + c);
        float4 xc = *(const float4*)(x + row * CH + c + 4);
        float2 stA = gstat[c >> 2];
        float2 stB = gstat[(c >> 2) + 1];
        float4 sA = *(const float4*)(gsc + c), sB = *(const float4*)(gsc + c + 4);
        float4 bA = *(const float4*)(gbi + c), bB = *(const float4*)(gbi + c + 4);
        ushort_t tmp[8];
        tmp[0] = f2bf((xa.x - stA.x) * stA.y * sA.x + bA.x);
        tmp[1] = f2bf((xa.y - stA.x) * stA.y * sA.y + bA.y);
        tmp[2] = f2bf((xa.z - stA.x) * stA.y * sA.z + bA.z);
        tmp[3] = f2bf((xa.w - stA.x) * stA.y * sA.w + bA.w);
        tmp[4] = f2bf((xc.x - stB.x) * stB.y * sB.x + bB.x);
        tmp[5] = f2bf((xc.y - stB.x) * stB.y * sB.y + bB.y);
        tmp[6] = f2bf((xc.z - stB.x) * stB.y * sB.z + bB.z);
        tmp[7] = f2bf((xc.w - stB.x) * stB.y * sB.w + bB.w);
        *(uint4*)&lds_a[r][c] = *(const uint4*)tmp;
    }
    for (int j = 0; j < 3; ++j) {
        const float* W  = (j == 0) ? Wq : (j == 1) ? Wk : Wv;
        const float* Bi = (j == 0) ? Bq : (j == 1) ? Bk : Bv;
        f32x4 acc[2][8] = {};
        for (int kh = 0; kh < 2; ++kh) {
            int k0 = kh * 64;
            __syncthreads();   // protect lds_w reuse (also orders A staging before first read)
            for (int i = 0; i < 8; ++i) {
                int idx = (t + i * 256) * 4;     // flat = kl*128 + n
                int kl = idx >> 7, n = idx & 127;
                float4 wf = *(const float4*)(W + (size_t)(k0 + kl) * CH + n);
                lds_w[n + 0][kl] = f2bf(wf.x);
                lds_w[n + 1][kl] = f2bf(wf.y);
                lds_w[n + 2][kl] = f2bf(wf.z);
                lds_w[n + 3][kl] = f2bf(wf.w);
            }
            __syncthreads();
            for (int ks = 0; ks < 2; ++ks) {
                bf16x8 afrag[2];
                for (int tr = 0; tr < 2; ++tr)
                    afrag[tr] = *(const bf16x8*)&lds_a[wv * 32 + tr * 16 + l16][k0 + ks * 32 + quad * 8];
                for (int tc = 0; tc < 8; ++tc) {
                    bf16x8 bfrag = *(const bf16x8*)&lds_w[tc * 16 + l16][ks * 32 + quad * 8];
                    for (int tr = 0; tr < 2; ++tr)
                        acc[tr][tc] = MFMA32(afrag[tr], bfrag, acc[tr][tc]);
                }
            }
        }
        // epilogue
        for (int tc = 0; tc < 8; ++tc) {
            int col = tc * 16 + l16;
            float bval = Bi[col];
            for (int tr = 0; tr < 2; ++tr) {
                int rl = wv * 32 + tr * 16 + quad * 4;
                for (int r = 0; r < 4; ++r) {
                    float vv = acc[tr][tc][r] + bval;
                    if (j == 0) vv *= C2;   // fold softmax scale into q
                    if (j == 2) {
                        outvt[(size_t)batch * CH * SEQ + (size_t)col * SEQ + seq0 + rl + r] = f2bf(vv);
                    } else {
                        ushort_t* op = (j == 0) ? outq : outk;
                        op[(m0 + rl + r) * CH + col] = f2bf(vv);
                    }
                }
            }
        }
    }
}

// ---------------- flash attention r15: CROSS-ITERATION PIPELINE --------------
// r14 post-mortem: 192us with real MFMA-pipe busy only ~9% (137.4 GFLOP / 192us
// = 715 TF incl. both pipes; 40k MFMA cycles vs 461k wall per SIMD), LDS ~42%,
// VALU 43% -> bound by the per-iteration SERIAL chain QK->softmax->PV->stage->
// barrier at 2 waves/SIMD.  Fix: pipeline across iterations.  K is staged one
// tile AHEAD of V (opposite buffer parity); pkp_i stays live across the
// barrier; the body fuses QK(tile i+1) with PV(tile i) — two independent MFMA
// dep-streams interleaved back-to-back — and softmax(i+1) runs after, hiding
// under the staging-write/barrier tail.  Parity: iter it reads lds_k[(it+1)&1]
// + lds_vt[it&1], writes K_{it+2}->lds_k[it&1], V_{it+1}->lds_vt[(it+1)&1];
// always opposite parity, single barrier/iter.  Unnormalized exp2 softmax
// (r14-proven numerics).
__global__ __launch_bounds__(256, 2) void flash_attn15(const ushort_t* __restrict__ q,
                                                       const ushort_t* __restrict__ k,
                                                       const ushort_t* __restrict__ vt,
                                                       ushort_t* __restrict__ o) {
    int bid = blockIdx.x;
    int b = bid & 15, qt = bid >> 4;
    int t = threadIdx.x;
    int wv = t >> 6, lane = t & 63, quad = lane >> 4, l16 = lane & 15;
    const size_t SB = (size_t)SEQ * CH;
    const ushort_t* qb  = q  + (size_t)b * SB;
    const ushort_t* kb  = k  + (size_t)b * SB;
    const ushort_t* vtb = vt + (size_t)b * SB;   // [d][seq]

    __shared__ ushort_t lds_k[2][64][136];    // [buf][key][d]
    __shared__ ushort_t lds_vt[2][128][72];   // [buf][d][key_local PERMUTED]

    int qrow_base = qt * 128 + wv * 32;       // 4 waves x 32 q-rows
    // Q^T B-fragments for both 16-row halves (n=qrow=l16, k=d=quad*8+j)
    bf16x8 qfrag[2][4];
#pragma unroll
    for (int nt = 0; nt < 2; ++nt)
#pragma unroll
        for (int ks = 0; ks < 4; ++ks)
            qfrag[nt][ks] = *(const bf16x8*)(qb + (size_t)(qrow_base + nt * 16 + l16) * CH + ks * 32 + quad * 8);

    f32x4 oacc[8][2] = {};        // [mt=d/16][nt]
    float psum[2] = {0.f, 0.f};   // per-lane partial row-sums (reduced at end)

    // staging geometry (256 threads stage the full 64-key K and V^T tiles:
    // 4 rounds of 16B each)
    int kr_row  = t >> 4;          // 0..15 (+16i)
    int kr_col  = (t & 15) * 8;
    int vr_d    = t >> 3;          // 0..31 (+32i)
    int vr_beta = t & 7;
    int vc0 = 32 * (vr_beta >> 2) + 16 * (vr_beta & 1) + 4 * ((vr_beta >> 1) & 1);

    const ushort_t* kp = kb + (size_t)kr_row * CH + kr_col;
    const ushort_t* vp = vtb + (size_t)vr_d * SEQ + vr_beta * 8;

    uint4 kr[4], vr[4], k1[4];
    // prologue: load K0, V0, K1; write K0->lds_k[0], V0->lds_vt[0], K1->lds_k[1]
#pragma unroll
    for (int i = 0; i < 4; ++i) kr[i] = *(const uint4*)(kp + (size_t)i * 16 * CH);
#pragma unroll
    for (int i = 0; i < 4; ++i) vr[i] = *(const uint4*)(vp + (size_t)i * 32 * SEQ);
#pragma unroll
    for (int i = 0; i < 4; ++i) k1[i] = *(const uint4*)(kp + (size_t)(64 + i * 16) * CH);
    kp += 2 * 64 * CH;   // -> tile 2
    vp += 64;            // -> tile 1
#pragma unroll
    for (int i = 0; i < 4; ++i) {
        *(uint4*)&lds_k[0][kr_row + 16 * i][kr_col] = kr[i];
        *(uint4*)&lds_k[1][kr_row + 16 * i][kr_col] = k1[i];
        *(uint2*)&lds_vt[0][vr_d + 32 * i][vc0]     = uint2{vr[i].x, vr[i].y};
        *(uint2*)&lds_vt[0][vr_d + 32 * i][vc0 + 8] = uint2{vr[i].z, vr[i].w};
    }
    __syncthreads();

    // prologue compute: QK_0 -> pkp_0 (unnormalized exp2)
    bf16x8 pkp[2][2];   // [nt][half], live across iterations
    {
        f32x4 s[4][2] = {};
#pragma unroll
        for (int ks = 0; ks < 4; ++ks) {
            bf16x8 kf[4];
#pragma unroll
            for (int kt = 0; kt < 4; ++kt)
                kf[kt] = *(const bf16x8*)&lds_k[0][kt * 16 + l16][ks * 32 + quad * 8];
#pragma unroll
            for (int kt = 0; kt < 4; ++kt) {
                s[kt][0] = MFMA32(kf[kt], qfrag[0][ks], s[kt][0]);
                s[kt][1] = MFMA32(kf[kt], qfrag[1][ks], s[kt][1]);
            }
        }
#pragma unroll
        for (int nt = 0; nt < 2; ++nt) {
            float ps = 0.f;
            uint_t pb[8];
#pragma unroll
            for (int kt = 0; kt < 4; ++kt) {
                float p0 = exp2f(s[kt][nt][0]);
                float p1 = exp2f(s[kt][nt][1]);
                float p2 = exp2f(s[kt][nt][2]);
                float p3 = exp2f(s[kt][nt][3]);
                ps += (p0 + p1) + (p2 + p3);
                __hip_bfloat162 h01 = __float22bfloat162_rn(float2{p0, p1});
                __hip_bfloat162 h23 = __float22bfloat162_rn(float2{p2, p3});
                __builtin_memcpy(&pb[kt * 2 + 0], &h01, 4);
                __builtin_memcpy(&pb[kt * 2 + 1], &h23, 4);
            }
            psum[nt] += ps;
            __builtin_memcpy(&pkp[nt][0], &pb[0], 16);
            __builtin_memcpy(&pkp[nt][1], &pb[4], 16);
        }
    }
    __syncthreads();   // all waves done reading lds_k[0] before iter0 overwrites it

    // main loop: iter it computes PV(tile it) + QK(tile it+1)
    for (int it = 0; it < 63; ++it) {
        int knxt = (it + 1) & 1;   // K_{it+1} read buffer; also V_{it+1} write buffer
        int vcur = it & 1;         // V_it read buffer;    also K_{it+2} write buffer
        // issue loads: K_{it+2}, V_{it+1} (it=62 reads K one tile past the end:
        // lands in the adjacent vt workspace buffer, values never used)
#pragma unroll
        for (int i = 0; i < 4; ++i) kr[i] = *(const uint4*)(kp + (size_t)i * 16 * CH);
#pragma unroll
        for (int i = 0; i < 4; ++i) vr[i] = *(const uint4*)(vp + (size_t)i * 32 * SEQ);
        kp += 64 * CH; vp += 64;

        // fused MFMA block: QK_{it+1} (lds_k[knxt]) interleaved with
        // PV_it (lds_vt[vcur], pkp from previous iteration) — independent
        // dep-streams, back-to-back MFMA issue.
        f32x4 s[4][2] = {};
#pragma unroll
        for (int u = 0; u < 4; ++u) {
            bf16x8 kf[4];
#pragma unroll
            for (int kt = 0; kt < 4; ++kt)
                kf[kt] = *(const bf16x8*)&lds_k[knxt][kt * 16 + l16][u * 32 + quad * 8];
#pragma unroll
            for (int kt = 0; kt < 4; ++kt) {
                s[kt][0] = MFMA32(kf[kt], qfrag[0][u], s[kt][0]);
                s[kt][1] = MFMA32(kf[kt], qfrag[1][u], s[kt][1]);
            }
#pragma unroll
            for (int m2 = 0; m2 < 2; ++m2) {
                int mt = u * 2 + m2;
                bf16x8 vf0 = *(const bf16x8*)&lds_vt[vcur][mt * 16 + l16][quad * 8];
                bf16x8 vf1 = *(const bf16x8*)&lds_vt[vcur][mt * 16 + l16][32 + quad * 8];
                oacc[mt][0] = MFMA32(vf0, pkp[0][0], oacc[mt][0]);
                oacc[mt][0] = MFMA32(vf1, pkp[0][1], oacc[mt][0]);
                oacc[mt][1] = MFMA32(vf0, pkp[1][0], oacc[mt][1]);
                oacc[mt][1] = MFMA32(vf1, pkp[1][1], oacc[mt][1]);
            }
        }

        // softmax(tile it+1) -> pkp for next iteration (overlaps store tail)
#pragma unroll
        for (int nt = 0; nt < 2; ++nt) {
            float ps = 0.f;
            uint_t pb[8];
#pragma unroll
            for (int kt = 0; kt < 4; ++kt) {
                float p0 = exp2f(s[kt][nt][0]);
                float p1 = exp2f(s[kt][nt][1]);
                float p2 = exp2f(s[kt][nt][2]);
                float p3 = exp2f(s[kt][nt][3]);
                ps += (p0 + p1) + (p2 + p3);
                __hip_bfloat162 h01 = __float22bfloat162_rn(float2{p0, p1});
                __hip_bfloat162 h23 = __float22bfloat162_rn(float2{p2, p3});
                __builtin_memcpy(&pb[kt * 2 + 0], &h01, 4);
                __builtin_memcpy(&pb[kt * 2 + 1], &h23, 4);
            }
            psum[nt] += ps;
            __builtin_memcpy(&pkp[nt][0], &pb[0], 16);
            __builtin_memcpy(&pkp[nt][1], &pb[4], 16);
        }

        // stage writes: K_{it+2} -> lds_k[vcur], V_{it+1} -> lds_vt[knxt]
        // (both regions last READ in iter it-1; ordered by that barrier)
#pragma unroll
        for (int i = 0; i < 4; ++i) {
            *(uint4*)&lds_k[vcur][kr_row + 16 * i][kr_col] = kr[i];
            *(uint2*)&lds_vt[knxt][vr_d + 32 * i][vc0]     = uint2{vr[i].x, vr[i].y};
            *(uint2*)&lds_vt[knxt][vr_d + 32 * i][vc0 + 8] = uint2{vr[i].z, vr[i].w};
        }
        __syncthreads();   // single barrier per iteration
    }

    // epilogue: PV for tile 63 (lds_vt[1], pkp_63 computed at it=62)
#pragma unroll
    for (int mt = 0; mt < 8; ++mt) {
        bf16x8 vf0 = *(const bf16x8*)&lds_vt[1][mt * 16 + l16][quad * 8];
        bf16x8 vf1 = *(const bf16x8*)&lds_vt[1][mt * 16 + l16][32 + quad * 8];
        oacc[mt][0] = MFMA32(vf0, pkp[0][0], oacc[mt][0]);
        oacc[mt][0] = MFMA32(vf1, pkp[0][1], oacc[mt][0]);
        oacc[mt][1] = MFMA32(vf0, pkp[1][0], oacc[mt][1]);
        oacc[mt][1] = MFMA32(vf1, pkp[1][1], oacc[mt][1]);
    }

    // epilogue: cross-lane row-sum reduce (ONCE), then O[qrow][d] = O^T / l
#pragma unroll
    for (int nt = 0; nt < 2; ++nt) {
        float tot = psum[nt];
        tot += __shfl_xor(tot, 16, 64);
        tot += __shfl_xor(tot, 32, 64);
        float inv = 1.f / tot;
        size_t row = (size_t)b * SEQ + qrow_base + nt * 16 + l16;
#pragma unroll
        for (int mt = 0; mt < 8; ++mt) {
            ushort_t tmp[4];
#pragma unroll
            for (int r = 0; r < 4; ++r) tmp[r] = f2bf(oacc[mt][nt][r] * inv);
            *(uint2*)&o[row * CH + mt * 16 + quad * 4] = *(const uint2*)tmp;
        }
    }
}

// ---------------- final GEMM: out = A_bf16 @ W + bias + resid (fp32 out) ----------------
__global__ __launch_bounds__(256) void gemm_out(const ushort_t* __restrict__ A,
                                                const float* __restrict__ W,
                                                const float* __restrict__ bias,
                                                const float* __restrict__ resid,
                                                float* __restrict__ out) {
    __shared__ ushort_t lds_a[128][72];
    __shared__ ushort_t lds_w[128][72];
    int t = threadIdx.x;
    int wv = t >> 6, lane = t & 63, quad = lane >> 4, l16 = lane & 15;
    size_t m0 = (size_t)blockIdx.x * 128;
    f32x4 acc[2][8] = {};
    for (int kh = 0; kh < 2; ++kh) {
        int k0 = kh * 64;
        __syncthreads();
        for (int i = 0; i < 4; ++i) {
            int idx = (t + i * 256) * 8;
            int r = idx >> 6, c = idx & 63;
            *(uint4*)&lds_a[r][c] = *(const uint4*)(A + (m0 + r) * CH + k0 + c);
        }
        for (int i = 0; i < 8; ++i) {
            int idx = (t + i * 256) * 4;
            int kl = idx >> 7, n = idx & 127;
            float4 wf = *(const float4*)(W + (size_t)(k0 + kl) * CH + n);
            lds_w[n + 0][kl] = f2bf(wf.x);
            lds_w[n + 1][kl] = f2bf(wf.y);
            lds_w[n + 2][kl] = f2bf(wf.z);
            lds_w[n + 3][kl] = f2bf(wf.w);
        }
        __syncthreads();
        for (int ks = 0; ks < 2; ++ks) {
            bf16x8 afrag[2];
            for (int tr = 0; tr < 2; ++tr)
                afrag[tr] = *(const bf16x8*)&lds_a[wv * 32 + tr * 16 + l16][ks * 32 + quad * 8];
            for (int tc = 0; tc < 8; ++tc) {
                bf16x8 bfrag = *(const bf16x8*)&lds_w[tc * 16 + l16][ks * 32 + quad * 8];
                for (int tr = 0; tr < 2; ++tr)
                    acc[tr][tc] = MFMA32(afrag[tr], bfrag, acc[tr][tc]);
            }
        }
    }
    for (int tc = 0; tc < 8; ++tc) {
        int col = tc * 16 + l16;
        float bval = bias[col];
        for (int tr = 0; tr < 2; ++tr) {
            int rl = wv * 32 + tr * 16 + quad * 4;
            for (int r = 0; r < 4; ++r) {
                size_t row = m0 + rl + r;
                out[row * CH + col] = acc[tr][tc][r] + bval + resid[row * CH + col];
            }
        }
    }
}

extern "C" void kernel_launch(void* const* d_in, const int* in_sizes, int n_in,
                              void* d_out, int out_size, void* d_ws, size_t ws_size,
                              hipStream_t stream) {
    const float* x   = (const float*)d_in[0];
    const float* gsc = (const float*)d_in[1];
    const float* gbi = (const float*)d_in[2];
    const float* wq  = (const float*)d_in[3];
    const float* bq  = (const float*)d_in[4];
    const float* wk  = (const float*)d_in[5];
    const float* bk  = (const float*)d_in[6];
    const float* wvp = (const float*)d_in[7];
    const float* bv  = (const float*)d_in[8];
    const float* wo  = (const float*)d_in[9];
    const float* bo  = (const float*)d_in[10];
    float* outp = (float*)d_out;

    const size_t NELEM = (size_t)BATCH * SEQ * CH;  // 8388608
    float*    stats = (float*)d_ws;
    ushort_t* qbuf  = (ushort_t*)((char*)d_ws + 4096);
    ushort_t* kbuf  = qbuf + NELEM;
    ushort_t* vtbuf = kbuf + NELEM;
    ushort_t* abuf  = vtbuf + NELEM;   // attention output
    // note: flash_attn15 prefetches one K tile past the K buffer end (reads
    // land in vtbuf; values unused) — keep buffer order qbuf,kbuf,vtbuf,abuf.

    hipMemsetAsync(stats, 0, BATCH * NGRP * 2 * sizeof(float), stream);
    gn_partial<<<256, 256, 0, stream>>>(x, stats);
    gemm_qkv<<<512, 256, 0, stream>>>(x, stats, gsc, gbi, wq, wk, wvp, bq, bk, bv,
                                      qbuf, kbuf, vtbuf);
    flash_attn15<<<512, 256, 0, stream>>>(qbuf, kbuf, vtbuf, abuf);
    gemm_out<<<512, 256, 0, stream>>>(abuf, wo, bo, x, outp);
}